// Round 3
// baseline (228.238 us; speedup 1.0000x reference)
//
#include <hip/hip_runtime.h>
#include <hip/hip_bf16.h>

typedef float  f32x4  __attribute__((ext_vector_type(4)));
typedef __bf16 bf16x8 __attribute__((ext_vector_type(8)));

#define MFMA16(A,B,C) __builtin_amdgcn_mfma_f32_16x16x32_bf16((A),(B),(C),0,0,0)

constexpr int BN = 16, HN = 8, LN = 128, DN = 64;
constexpr size_t OUT0 = (size_t)BN * HN * BN * LN * DN;  // O elements; attn follows

constexpr int QE = BN * HN * LN * DN;                    // 1,048,576 elems per plane
constexpr size_t MBOFF = 4 * (size_t)QE;                 // bf16 elems: mask plane offset
constexpr size_t WS_BYTES = (MBOFF + (size_t)BN * LN * LN) * sizeof(__bf16);  // 8.5 MiB

constexpr int PS  = 36;   // P row stride (fp32) = 144 B (scatter stays 2-way/free)
// fallback-path strides (original kernel)
constexpr int KTS = 72;
constexpr int VTS = 136;

// ---------- helpers ----------

__device__ __forceinline__ void load8_split(const float* __restrict__ p, float scale,
                                            bf16x8& hi, bf16x8& lo) {
  float f[8];
  *(float4*)&f[0] = *(const float4*)(p);
  *(float4*)&f[4] = *(const float4*)(p + 4);
#pragma unroll
  for (int i = 0; i < 8; ++i) {
    float x = f[i] * scale;
    __bf16 h = (__bf16)x;
    hi[i] = h;
    lo[i] = (__bf16)(x - (float)h);
  }
}

__device__ __forceinline__ void lds8_split(const float* p, bf16x8& hi, bf16x8& lo) {
  float f[8];
  *(float4*)&f[0] = *(const float4*)(p);
  *(float4*)&f[4] = *(const float4*)(p + 4);
#pragma unroll
  for (int i = 0; i < 8; ++i) {
    __bf16 h = (__bf16)f[i];
    hi[i] = h;
    lo[i] = (__bf16)(f[i] - (float)h);
  }
}

// width-16 global -> LDS DMA (linear dest = wave-uniform base + lane*16)
__device__ __forceinline__ void gload_lds16(const void* g, void* l) {
  __builtin_amdgcn_global_load_lds(
      (const __attribute__((address_space(1))) unsigned int*)g,
      (__attribute__((address_space(3))) unsigned int*)l, 16, 0, 0);
}

// nontemporal 16B ops use clang ext-vector types (HIP_vector_type is rejected)
__device__ __forceinline__ f32x4 ntld4(const float* p) {
  return __builtin_nontemporal_load((const f32x4*)p);
}
__device__ __forceinline__ void ntst4(float* p, f32x4 v) {
  __builtin_nontemporal_store(v, (f32x4*)p);
}

// ---------- pre-pass: convert/split/transpose once (shared by 16 blocks each) ----------
// ws layout (bf16 elems): [0,QE) Qhi | [QE,2QE) Qlo | [2QE,3QE) KT | [3QE,4QE) VT
//                         [4QE, 4QE+16*16384) mask repacked to lane layout
// KT/VT are stored XOR-swizzled (elem-group ^= (row&7)<<3) so the main kernel's
// LINEAR global_load_lds deposits a swizzled LDS image and ds_read XORs it back.
__global__ __launch_bounds__(256) void pre_kernel(
    const float* __restrict__ Q, const float* __restrict__ K,
    const float* __restrict__ V, const int* __restrict__ M,
    __bf16* __restrict__ ws)
{
  const int t   = threadIdx.x;
  const int blk = blockIdx.x;

  if (blk < 512) {
    // ---- Q: pre-scaled hi/lo split, layout preserved (B,H,L,D) ----
    int base = blk * 2048 + t * 8;
    float f[8];
    *(f32x4*)&f[0] = ntld4(Q + base);
    *(f32x4*)&f[4] = ntld4(Q + base + 4);
    bf16x8 hi, lo;
#pragma unroll
    for (int i = 0; i < 8; ++i) {
      float x = f[i] * 0.125f;
      __bf16 h = (__bf16)x;
      hi[i] = h;
      lo[i] = (__bf16)(x - (float)h);
    }
    *(bf16x8*)&ws[base]      = hi;
    *(bf16x8*)&ws[QE + base] = lo;
  } else if (blk < 1024) {
    // ---- K -> bf16, k-group swizzled within each row ----
    int g  = (blk - 512) * 256 + t;      // bits: [0:2]=k-group [3:9]=n [10:16]=hc
    int k0 = (g & 7) * 8;
    int n  = (g >> 3) & 127;
    int hc = g >> 10;
    const float* src = K + ((size_t)hc * LN + n) * DN + k0;
    float f[8];
    *(f32x4*)&f[0] = ntld4(src);
    *(f32x4*)&f[4] = ntld4(src + 4);
    bf16x8 kk;
#pragma unroll
    for (int i = 0; i < 8; ++i) kk[i] = (__bf16)f[i];
    int k0s = k0 ^ ((n & 7) << 3);
    *(bf16x8*)&ws[2 * (size_t)QE + (size_t)hc * 8192 + n * 64 + k0s] = kk;
  } else if (blk < 1152) {
    // ---- V -> V^T bf16 [d][j], j-group swizzled within each row ----
    int hc = blk - 1024;
    int j8 = t >> 4;                 // j block of 8
    int d0 = (t & 15) * 4;
    const float* Vp = V + (size_t)hc * (LN * DN);
    f32x4 vv[8];
#pragma unroll
    for (int r = 0; r < 8; ++r)
      vv[r] = ntld4(Vp + (j8 * 8 + r) * DN + d0);
#pragma unroll
    for (int dw = 0; dw < 4; ++dw) {
      int d = d0 + dw;
      bf16x8 col;
#pragma unroll
      for (int r = 0; r < 8; ++r)
        col[r] = (__bf16)vv[r][dw];
      int js = (j8 * 8) ^ ((d & 7) << 3);
      *(bf16x8*)&ws[3 * (size_t)QE + (size_t)hc * 8192 + d * 128 + js] = col;
    }
  } else {
    // ---- mask repack: Mb[b][row][l16*8+ct] = (bf16)M[b][row][ct*16+l16] ----
    // softmax then needs ONE bf16x8 load per row instead of 8 strided scalars
    int bsel = blk - 1152;
    const int* src = M + (size_t)bsel * (LN * LN);
    __bf16*    dst = ws + MBOFF + (size_t)bsel * (LN * LN);
    int row  = t >> 1;
    int half = t & 1;
#pragma unroll
    for (int g = 0; g < 8; ++g) {
      int l16 = half * 8 + g;
      bf16x8 m8;
#pragma unroll
      for (int ct = 0; ct < 8; ++ct)
        m8[ct] = (__bf16)(float)src[row * LN + ct * 16 + l16];
      *(bf16x8*)&dst[row * LN + l16 * 8] = m8;
    }
  }
}

// ---------- fast main kernel: DMA staging, packed mask, nontemporal outputs ----------
__global__ __launch_bounds__(256, 3) void isa_attn_fast(
    const __bf16* __restrict__ ws, float* __restrict__ out)
{
  __shared__ __bf16 KT[LN * DN];   // 16384 B, swizzled image
  __shared__ __bf16 VT[DN * LN];   // 16384 B, swizzled image
  __shared__ float  P [LN * PS];   // 18432 B
  // total 51200 B -> 3 blocks/CU (VGPR-capped at 3 waves/SIMD anyway)

  const int bid = blockIdx.x;
  // XCD swizzle: each XCD owns one h -> K,V(h,*) + Q(*,h) + mask fit its L2
  const int w = (bid & 7) * 256 + (bid >> 3);
  const int h = w >> 8;
  const int c = (w >> 4) & 15;
  const int b = w & 15;
  const int hc = h * BN + c;

  const __bf16* Qh = ws + (size_t)(b * HN + h) * (LN * DN);
  const __bf16* Ql = Qh + QE;
  const __bf16* Ks = ws + 2 * (size_t)QE + (size_t)hc * 8192;
  const __bf16* Vs = ws + 3 * (size_t)QE + (size_t)hc * 8192;
  const __bf16* Mb = ws + MBOFF + (size_t)b * (LN * LN);
  float* Op = out + (size_t)((b * HN + h) * BN + c) * (LN * DN);
  float* Wp = out + OUT0 + (size_t)((b * HN + h) * BN + c) * (LN * LN);

  const int t    = threadIdx.x;
  const int lane = t & 63;
  const int wid  = t >> 6;
  const int quad = lane >> 4;
  const int l16  = lane & 15;
  const int row0 = wid * 32;
  const int swz  = (l16 & 7) << 3;

  // ---- stage K / V^T via direct-to-LDS DMA ----
  {
    const char* kg = (const char*)Ks;
    const char* vg = (const char*)Vs;
    char* kl = (char*)KT;
    char* vl = (char*)VT;
#pragma unroll
    for (int i = 0; i < 4; ++i)
      gload_lds16(kg + t * 16 + i * 4096, kl + t * 16 + i * 4096);
#pragma unroll
    for (int i = 0; i < 4; ++i)
      gload_lds16(vg + t * 16 + i * 4096, vl + t * 16 + i * 4096);
  }

  // ---- Q A-fragments: direct bf16 loads (pre-scaled, pre-split) ----
  bf16x8 qhi[2][2], qlo[2][2];
#pragma unroll
  for (int rt = 0; rt < 2; ++rt)
#pragma unroll
    for (int kt = 0; kt < 2; ++kt) {
      const int off = (row0 + rt * 16 + l16) * DN + kt * 32 + quad * 8;
      qhi[rt][kt] = *(const bf16x8*)(Qh + off);
      qlo[rt][kt] = *(const bf16x8*)(Ql + off);
    }

  __syncthreads();   // drains vmcnt: DMA deposits complete

  // ---- S = (Qhi+Qlo) K^T ----
  f32x4 acc[2][8];
#pragma unroll
  for (int rt = 0; rt < 2; ++rt)
#pragma unroll
    for (int ct = 0; ct < 8; ++ct)
      acc[rt][ct] = (f32x4){0.f, 0.f, 0.f, 0.f};

#pragma unroll
  for (int ct = 0; ct < 8; ++ct) {
#pragma unroll
    for (int kt = 0; kt < 2; ++kt) {
      bf16x8 kh = *(const bf16x8*)&KT[(ct * 16 + l16) * 64 + ((kt * 32 + quad * 8) ^ swz)];
#pragma unroll
      for (int rt = 0; rt < 2; ++rt) {
        acc[rt][ct] = MFMA16(qhi[rt][kt], kh, acc[rt][ct]);
        acc[rt][ct] = MFMA16(qlo[rt][kt], kh, acc[rt][ct]);
      }
    }
  }

  // ---- softmax (packed bf16 mask: one 16B load per row) ----
#pragma unroll
  for (int rt = 0; rt < 2; ++rt) {
    bf16x8 m8[4];
#pragma unroll
    for (int r = 0; r < 4; ++r) {
      int row = row0 + rt * 16 + quad * 4 + r;
      m8[r] = *(const bf16x8*)&Mb[row * LN + l16 * 8];
    }
#pragma unroll
    for (int r = 0; r < 4; ++r) {
      float mx = -3.0e38f;
#pragma unroll
      for (int ct = 0; ct < 8; ++ct) mx = fmaxf(mx, acc[rt][ct][r]);
      mx = fmaxf(mx, __shfl_xor(mx, 1));
      mx = fmaxf(mx, __shfl_xor(mx, 2));
      mx = fmaxf(mx, __shfl_xor(mx, 4));
      mx = fmaxf(mx, __shfl_xor(mx, 8));
      float s[8];
      float sum = 0.f;
#pragma unroll
      for (int ct = 0; ct < 8; ++ct) {
        s[ct] = __expf(acc[rt][ct][r] - mx) * (float)m8[r][ct];
        sum += s[ct];
      }
      sum += __shfl_xor(sum, 1);
      sum += __shfl_xor(sum, 2);
      sum += __shfl_xor(sum, 4);
      sum += __shfl_xor(sum, 8);
      float inv = __builtin_amdgcn_rcpf(sum);
      inv = inv * (2.0f - sum * inv);
#pragma unroll
      for (int ct = 0; ct < 8; ++ct) acc[rt][ct][r] = s[ct] * inv;
    }
  }

  f32x4 oacc[2][4];
#pragma unroll
  for (int rt = 0; rt < 2; ++rt)
#pragma unroll
    for (int nt = 0; nt < 4; ++nt)
      oacc[rt][nt] = (f32x4){0.f, 0.f, 0.f, 0.f};

  // ---- per column-quarter: scatter P, coalesced nt attn store, PV ----
#pragma unroll
  for (int qu = 0; qu < 4; ++qu) {
#pragma unroll
    for (int rt = 0; rt < 2; ++rt)
#pragma unroll
      for (int cc = 0; cc < 2; ++cc)
#pragma unroll
        for (int r = 0; r < 4; ++r)
          P[(row0 + rt * 16 + quad * 4 + r) * PS + cc * 16 + l16] =
              acc[rt][qu * 2 + cc][r];

#pragma unroll
    for (int e = 0; e < 4; ++e) {
      int idx = e * 64 + lane;      // 256 float4 = 32 rows x 8
      int rl  = idx >> 3;
      int c4  = idx & 7;
      f32x4 v = *(const f32x4*)&P[(row0 + rl) * PS + c4 * 4];
      ntst4(&Wp[(size_t)(row0 + rl) * LN + qu * 32 + c4 * 4], v);
    }

    bf16x8 phi[2], plo[2];
#pragma unroll
    for (int rt = 0; rt < 2; ++rt)
      lds8_split(&P[(row0 + rt * 16 + l16) * PS + quad * 8], phi[rt], plo[rt]);
#pragma unroll
    for (int nt = 0; nt < 4; ++nt) {
      bf16x8 vh = *(const bf16x8*)&VT[(nt * 16 + l16) * 128 + ((qu * 32 + quad * 8) ^ swz)];
#pragma unroll
      for (int rt = 0; rt < 2; ++rt) {
        oacc[rt][nt] = MFMA16(phi[rt], vh, oacc[rt][nt]);
        oacc[rt][nt] = MFMA16(plo[rt], vh, oacc[rt][nt]);
      }
    }
  }

  // ---- O: scatter to P (wave-private), then coalesced nt float4 store ----
#pragma unroll
  for (int hf = 0; hf < 2; ++hf) {
#pragma unroll
    for (int rt = 0; rt < 2; ++rt)
#pragma unroll
      for (int nn = 0; nn < 2; ++nn)
#pragma unroll
        for (int r = 0; r < 4; ++r)
          P[(row0 + rt * 16 + quad * 4 + r) * PS + nn * 16 + l16] =
              oacc[rt][hf * 2 + nn][r];
#pragma unroll
    for (int e = 0; e < 4; ++e) {
      int idx = e * 64 + lane;
      int rl  = idx >> 3;
      int c4  = idx & 7;
      f32x4 v = *(const f32x4*)&P[(row0 + rl) * PS + c4 * 4];
      ntst4(&Op[(size_t)(row0 + rl) * DN + hf * 32 + c4 * 4], v);
    }
  }
}

// ---------- fallback: original verified kernel (used if ws too small) ----------
__global__ __launch_bounds__(256, 3) void isa_attn_kernel(
    const float* __restrict__ Q, const float* __restrict__ K,
    const float* __restrict__ V, const int* __restrict__ M,
    float* __restrict__ out)
{
  __shared__ __bf16 KT[LN * KTS];
  __shared__ __bf16 VT[DN * VTS];
  __shared__ float  P [LN * PS];

  const int bid = blockIdx.x;
  const int w = (bid & 7) * 256 + (bid >> 3);
  const int h = w >> 8;
  const int c = (w >> 4) & 15;
  const int b = w & 15;

  const float* Qp = Q + (size_t)(b * HN + h) * (LN * DN);
  const float* Kp = K + (size_t)(h * BN + c) * (LN * DN);
  const float* Vp = V + (size_t)(h * BN + c) * (LN * DN);
  const int*   Mp = M + (size_t)b * (LN * LN);
  float* Op = out + (size_t)((b * HN + h) * BN + c) * (LN * DN);
  float* Wp = out + OUT0 + (size_t)((b * HN + h) * BN + c) * (LN * LN);

  const int t    = threadIdx.x;
  const int lane = t & 63;
  const int wid  = t >> 6;
  const int quad = lane >> 4;
  const int l16  = lane & 15;
  const int row0 = wid * 32;

#pragma unroll
  for (int it = 0; it < 4; ++it) {
    int idx = t + it * 256;
    int n  = idx >> 3;
    int k0 = (idx & 7) * 8;
    float4 a0 = *(const float4*)(Kp + n * DN + k0);
    float4 a1 = *(const float4*)(Kp + n * DN + k0 + 4);
    bf16x8 kk;
    kk[0] = (__bf16)a0.x; kk[1] = (__bf16)a0.y; kk[2] = (__bf16)a0.z; kk[3] = (__bf16)a0.w;
    kk[4] = (__bf16)a1.x; kk[5] = (__bf16)a1.y; kk[6] = (__bf16)a1.z; kk[7] = (__bf16)a1.w;
    *(bf16x8*)&KT[n * KTS + k0] = kk;
  }

  {
    int j8 = t >> 4;
    int d0 = (t & 15) * 4;
    float4 vv[8];
#pragma unroll
    for (int r = 0; r < 8; ++r)
      vv[r] = *(const float4*)(Vp + (j8 * 8 + r) * DN + d0);
#pragma unroll
    for (int dw = 0; dw < 4; ++dw) {
      bf16x8 col;
#pragma unroll
      for (int r = 0; r < 8; ++r)
        col[r] = (__bf16)(((const float*)&vv[r])[dw]);
      *(bf16x8*)&VT[(d0 + dw) * VTS + j8 * 8] = col;
    }
  }

  bf16x8 qhi[2][2], qlo[2][2];
#pragma unroll
  for (int rt = 0; rt < 2; ++rt)
#pragma unroll
    for (int kt = 0; kt < 2; ++kt)
      load8_split(Qp + (row0 + rt * 16 + l16) * DN + kt * 32 + quad * 8, 0.125f,
                  qhi[rt][kt], qlo[rt][kt]);

  __syncthreads();

  f32x4 acc[2][8];
#pragma unroll
  for (int rt = 0; rt < 2; ++rt)
#pragma unroll
    for (int ct = 0; ct < 8; ++ct)
      acc[rt][ct] = (f32x4){0.f, 0.f, 0.f, 0.f};

#pragma unroll
  for (int ct = 0; ct < 8; ++ct) {
#pragma unroll
    for (int kt = 0; kt < 2; ++kt) {
      bf16x8 kh = *(const bf16x8*)&KT[(ct * 16 + l16) * KTS + kt * 32 + quad * 8];
#pragma unroll
      for (int rt = 0; rt < 2; ++rt) {
        acc[rt][ct] = MFMA16(qhi[rt][kt], kh, acc[rt][ct]);
        acc[rt][ct] = MFMA16(qlo[rt][kt], kh, acc[rt][ct]);
      }
    }
  }

#pragma unroll
  for (int rt = 0; rt < 2; ++rt) {
#pragma unroll
    for (int r = 0; r < 4; ++r) {
      int row = row0 + rt * 16 + quad * 4 + r;
      const int* mrow = Mp + (size_t)row * LN + l16;
      float mf[8];
#pragma unroll
      for (int ct = 0; ct < 8; ++ct) mf[ct] = (float)mrow[ct * 16];
      float mx = -3.0e38f;
#pragma unroll
      for (int ct = 0; ct < 8; ++ct) mx = fmaxf(mx, acc[rt][ct][r]);
      mx = fmaxf(mx, __shfl_xor(mx, 1));
      mx = fmaxf(mx, __shfl_xor(mx, 2));
      mx = fmaxf(mx, __shfl_xor(mx, 4));
      mx = fmaxf(mx, __shfl_xor(mx, 8));
      float s[8];
      float sum = 0.f;
#pragma unroll
      for (int ct = 0; ct < 8; ++ct) {
        s[ct] = __expf(acc[rt][ct][r] - mx) * mf[ct];
        sum += s[ct];
      }
      sum += __shfl_xor(sum, 1);
      sum += __shfl_xor(sum, 2);
      sum += __shfl_xor(sum, 4);
      sum += __shfl_xor(sum, 8);
      float inv = __builtin_amdgcn_rcpf(sum);
      inv = inv * (2.0f - sum * inv);
#pragma unroll
      for (int ct = 0; ct < 8; ++ct) acc[rt][ct][r] = s[ct] * inv;
    }
  }

  f32x4 oacc[2][4];
#pragma unroll
  for (int rt = 0; rt < 2; ++rt)
#pragma unroll
    for (int nt = 0; nt < 4; ++nt)
      oacc[rt][nt] = (f32x4){0.f, 0.f, 0.f, 0.f};

#pragma unroll
  for (int qu = 0; qu < 4; ++qu) {
#pragma unroll
    for (int rt = 0; rt < 2; ++rt)
#pragma unroll
      for (int cc = 0; cc < 2; ++cc)
#pragma unroll
        for (int r = 0; r < 4; ++r)
          P[(row0 + rt * 16 + quad * 4 + r) * PS + cc * 16 + l16] =
              acc[rt][qu * 2 + cc][r];

#pragma unroll
    for (int e = 0; e < 4; ++e) {
      int idx = e * 64 + lane;
      int rl  = idx >> 3;
      int c4  = idx & 7;
      float4 v = *(const float4*)&P[(row0 + rl) * PS + c4 * 4];
      *(float4*)&Wp[(size_t)(row0 + rl) * LN + qu * 32 + c4 * 4] = v;
    }

    bf16x8 phi[2], plo[2];
#pragma unroll
    for (int rt = 0; rt < 2; ++rt)
      lds8_split(&P[(row0 + rt * 16 + l16) * PS + quad * 8], phi[rt], plo[rt]);
#pragma unroll
    for (int nt = 0; nt < 4; ++nt) {
      bf16x8 vh = *(const bf16x8*)&VT[(nt * 16 + l16) * VTS + qu * 32 + quad * 8];
#pragma unroll
      for (int rt = 0; rt < 2; ++rt) {
        oacc[rt][nt] = MFMA16(phi[rt], vh, oacc[rt][nt]);
        oacc[rt][nt] = MFMA16(plo[rt], vh, oacc[rt][nt]);
      }
    }
  }

#pragma unroll
  for (int hf = 0; hf < 2; ++hf) {
#pragma unroll
    for (int rt = 0; rt < 2; ++rt)
#pragma unroll
      for (int nn = 0; nn < 2; ++nn)
#pragma unroll
        for (int r = 0; r < 4; ++r)
          P[(row0 + rt * 16 + quad * 4 + r) * PS + nn * 16 + l16] =
              oacc[rt][hf * 2 + nn][r];
#pragma unroll
    for (int e = 0; e < 4; ++e) {
      int idx = e * 64 + lane;
      int rl  = idx >> 3;
      int c4  = idx & 7;
      float4 v = *(const float4*)&P[(row0 + rl) * PS + c4 * 4];
      *(float4*)&Op[(size_t)(row0 + rl) * DN + hf * 32 + c4 * 4] = v;
    }
  }
}

extern "C" void kernel_launch(void* const* d_in, const int* in_sizes, int n_in,
                              void* d_out, int out_size, void* d_ws, size_t ws_size,
                              hipStream_t stream) {
  const float* Q = (const float*)d_in[0];
  const float* K = (const float*)d_in[1];
  const float* V = (const float*)d_in[2];
  const int*   M = (const int*)d_in[3];
  if (d_ws != nullptr && ws_size >= WS_BYTES) {
    __bf16* ws = (__bf16*)d_ws;
    pre_kernel<<<dim3(1168), dim3(256), 0, stream>>>(Q, K, V, M, ws);
    isa_attn_fast<<<dim3(BN * HN * BN), dim3(256), 0, stream>>>(ws, (float*)d_out);
  } else {
    isa_attn_kernel<<<dim3(BN * HN * BN), dim3(256), 0, stream>>>(Q, K, V, M, (float*)d_out);
  }
}

// Round 5
// 222.509 us; speedup vs baseline: 1.0257x; 1.0257x over previous
//
#include <hip/hip_runtime.h>
#include <hip/hip_bf16.h>

typedef float  f32x4  __attribute__((ext_vector_type(4)));
typedef __bf16 bf16x8 __attribute__((ext_vector_type(8)));

#define MFMA16(A,B,C) __builtin_amdgcn_mfma_f32_16x16x32_bf16((A),(B),(C),0,0,0)

// full 16-lane butterfly via DPP (xor 15,7,3,1) — VALU-only, no LDS pipe
#define DPPI(x, ctrl) __int_as_float(__builtin_amdgcn_mov_dpp(__float_as_int(x), (ctrl), 0xF, 0xF, true))
#define DPP_MAX16(x) do { \
  x = fmaxf(x, DPPI(x, 0x140)); /* row_mirror      = xor15 */ \
  x = fmaxf(x, DPPI(x, 0x141)); /* row_half_mirror = xor7  */ \
  x = fmaxf(x, DPPI(x, 0x1B));  /* quad_perm 3210  = xor3  */ \
  x = fmaxf(x, DPPI(x, 0xB1));  /* quad_perm 1032  = xor1  */ \
} while (0)
#define DPP_SUM16(x) do { \
  x += DPPI(x, 0x140); \
  x += DPPI(x, 0x141); \
  x += DPPI(x, 0x1B);  \
  x += DPPI(x, 0xB1);  \
} while (0)

constexpr int BN = 16, HN = 8, LN = 128, DN = 64;
constexpr size_t OUT0 = (size_t)BN * HN * BN * LN * DN;  // O elements; attn follows

constexpr int QE = BN * HN * LN * DN;                    // 1,048,576 elems per plane
constexpr size_t MBOFF = 4 * (size_t)QE;                 // bf16 elems: mask plane offset
constexpr size_t WS_BYTES = (MBOFF + (size_t)BN * LN * LN) * sizeof(__bf16);  // 8.5 MiB

constexpr int PS  = 36;   // P row stride (fp32) = 144 B (scatter stays 2-way/free)
// fallback-path strides (original kernel)
constexpr int KTS = 72;
constexpr int VTS = 136;

// ---------- helpers ----------

__device__ __forceinline__ void load8_split(const float* __restrict__ p, float scale,
                                            bf16x8& hi, bf16x8& lo) {
  float f[8];
  *(float4*)&f[0] = *(const float4*)(p);
  *(float4*)&f[4] = *(const float4*)(p + 4);
#pragma unroll
  for (int i = 0; i < 8; ++i) {
    float x = f[i] * scale;
    __bf16 h = (__bf16)x;
    hi[i] = h;
    lo[i] = (__bf16)(x - (float)h);
  }
}

__device__ __forceinline__ void lds8_split(const float* p, bf16x8& hi, bf16x8& lo) {
  float f[8];
  *(float4*)&f[0] = *(const float4*)(p);
  *(float4*)&f[4] = *(const float4*)(p + 4);
#pragma unroll
  for (int i = 0; i < 8; ++i) {
    __bf16 h = (__bf16)f[i];
    hi[i] = h;
    lo[i] = (__bf16)(f[i] - (float)h);
  }
}

// width-16 global -> LDS DMA (linear dest = wave-uniform base + lane*16)
__device__ __forceinline__ void gload_lds16(const void* g, void* l) {
  __builtin_amdgcn_global_load_lds(
      (const __attribute__((address_space(1))) unsigned int*)g,
      (__attribute__((address_space(3))) unsigned int*)l, 16, 0, 0);
}

// nontemporal 16B ops use clang ext-vector types (HIP_vector_type is rejected)
__device__ __forceinline__ f32x4 ntld4(const float* p) {
  return __builtin_nontemporal_load((const f32x4*)p);
}
__device__ __forceinline__ void ntst4(float* p, f32x4 v) {
  __builtin_nontemporal_store(v, (f32x4*)p);
}

// ---------- pre-pass: convert/split/transpose once (shared by 16 blocks each) ----------
// ws layout (bf16 elems): [0,QE) Qhi | [QE,2QE) Qlo | [2QE,3QE) KT | [3QE,4QE) VT
//                         [4QE, 4QE+16*16384) mask repacked to lane layout
// KT/VT are stored XOR-swizzled (elem-group ^= (row&7)<<3) so the main kernel's
// LINEAR global_load_lds deposits a swizzled LDS image and ds_read XORs it back.
__global__ __launch_bounds__(256) void pre_kernel(
    const float* __restrict__ Q, const float* __restrict__ K,
    const float* __restrict__ V, const int* __restrict__ M,
    __bf16* __restrict__ ws)
{
  const int t   = threadIdx.x;
  const int blk = blockIdx.x;

  if (blk < 512) {
    // ---- Q: pre-scaled hi/lo split, layout preserved (B,H,L,D) ----
    int base = blk * 2048 + t * 8;
    float f[8];
    *(f32x4*)&f[0] = ntld4(Q + base);
    *(f32x4*)&f[4] = ntld4(Q + base + 4);
    bf16x8 hi, lo;
#pragma unroll
    for (int i = 0; i < 8; ++i) {
      float x = f[i] * 0.125f;
      __bf16 h = (__bf16)x;
      hi[i] = h;
      lo[i] = (__bf16)(x - (float)h);
    }
    *(bf16x8*)&ws[base]      = hi;
    *(bf16x8*)&ws[QE + base] = lo;
  } else if (blk < 1024) {
    // ---- K -> bf16, k-group swizzled within each row ----
    int g  = (blk - 512) * 256 + t;      // bits: [0:2]=k-group [3:9]=n [10:16]=hc
    int k0 = (g & 7) * 8;
    int n  = (g >> 3) & 127;
    int hc = g >> 10;
    const float* src = K + ((size_t)hc * LN + n) * DN + k0;
    float f[8];
    *(f32x4*)&f[0] = ntld4(src);
    *(f32x4*)&f[4] = ntld4(src + 4);
    bf16x8 kk;
#pragma unroll
    for (int i = 0; i < 8; ++i) kk[i] = (__bf16)f[i];
    int k0s = k0 ^ ((n & 7) << 3);
    *(bf16x8*)&ws[2 * (size_t)QE + (size_t)hc * 8192 + n * 64 + k0s] = kk;
  } else if (blk < 1152) {
    // ---- V -> V^T bf16 [d][j], j-group swizzled within each row ----
    int hc = blk - 1024;
    int j8 = t >> 4;                 // j block of 8
    int d0 = (t & 15) * 4;
    const float* Vp = V + (size_t)hc * (LN * DN);
    f32x4 vv[8];
#pragma unroll
    for (int r = 0; r < 8; ++r)
      vv[r] = ntld4(Vp + (j8 * 8 + r) * DN + d0);
#pragma unroll
    for (int dw = 0; dw < 4; ++dw) {
      int d = d0 + dw;
      bf16x8 col;
#pragma unroll
      for (int r = 0; r < 8; ++r)
        col[r] = (__bf16)vv[r][dw];
      int js = (j8 * 8) ^ ((d & 7) << 3);
      *(bf16x8*)&ws[3 * (size_t)QE + (size_t)hc * 8192 + d * 128 + js] = col;
    }
  } else {
    // ---- mask repack: Mb[b][row][l16*8+ct] = (bf16)M[b][row][ct*16+l16] ----
    int bsel = blk - 1152;
    const int* src = M + (size_t)bsel * (LN * LN);
    __bf16*    dst = ws + MBOFF + (size_t)bsel * (LN * LN);
    int row  = t >> 1;
    int half = t & 1;
#pragma unroll
    for (int g = 0; g < 8; ++g) {
      int l16 = half * 8 + g;
      bf16x8 m8;
#pragma unroll
      for (int ct = 0; ct < 8; ++ct)
        m8[ct] = (__bf16)(float)src[row * LN + ct * 16 + l16];
      *(bf16x8*)&dst[row * LN + l16 * 8] = m8;
    }
  }
}

// ---------- fast main kernel: 8 waves x 16 rows, 4 waves/SIMD occupancy ----------
__global__ __launch_bounds__(512, 4) void isa_attn_fast(
    const __bf16* __restrict__ ws, float* __restrict__ out)
{
  __shared__ __bf16 KT[LN * DN];   // 16384 B, swizzled image
  __shared__ __bf16 VT[DN * LN];   // 16384 B, swizzled image
  __shared__ float  P [LN * PS];   // 18432 B
  // total 51200 B; VGPR <= 128 -> 2 blocks/CU = 16 waves/CU = 4 waves/SIMD

  const int bid = blockIdx.x;
  // XCD swizzle: each XCD owns one h -> K,V(h,*) + Q(*,h) + mask fit its L2
  const int w = (bid & 7) * 256 + (bid >> 3);
  const int h = w >> 8;
  const int c = (w >> 4) & 15;
  const int b = w & 15;
  const int hc = h * BN + c;

  const __bf16* Qh = ws + (size_t)(b * HN + h) * (LN * DN);
  const __bf16* Ql = Qh + QE;
  const __bf16* Ks = ws + 2 * (size_t)QE + (size_t)hc * 8192;
  const __bf16* Vs = ws + 3 * (size_t)QE + (size_t)hc * 8192;
  const __bf16* Mb = ws + MBOFF + (size_t)b * (LN * LN);
  float* Op = out + (size_t)((b * HN + h) * BN + c) * (LN * DN);
  float* Wp = out + OUT0 + (size_t)((b * HN + h) * BN + c) * (LN * LN);

  const int t    = threadIdx.x;
  const int lane = t & 63;
  const int wid  = t >> 6;          // 8 waves; wave owns rows [16*wid, 16*wid+16)
  const int quad = lane >> 4;
  const int l16  = lane & 15;
  const int row0 = wid * 16;
  const int swz  = (l16 & 7) << 3;

  // ---- stage K / V^T via direct-to-LDS DMA (512 threads: 2+2 DMAs each) ----
  {
    const char* kg = (const char*)Ks;
    const char* vg = (const char*)Vs;
    char* kl = (char*)KT;
    char* vl = (char*)VT;
#pragma unroll
    for (int i = 0; i < 2; ++i)
      gload_lds16(kg + t * 16 + i * 8192, kl + t * 16 + i * 8192);
#pragma unroll
    for (int i = 0; i < 2; ++i)
      gload_lds16(vg + t * 16 + i * 8192, vl + t * 16 + i * 8192);
  }

  // ---- Q A-fragments: direct bf16 loads (pre-scaled, pre-split) ----
  bf16x8 qhi[2], qlo[2];
#pragma unroll
  for (int kt = 0; kt < 2; ++kt) {
    const int off = (row0 + l16) * DN + kt * 32 + quad * 8;
    qhi[kt] = *(const bf16x8*)(Qh + off);
    qlo[kt] = *(const bf16x8*)(Ql + off);
  }

  __syncthreads();   // drains vmcnt: DMA deposits complete

  // ---- S = (Qhi+Qlo) K^T ----
  f32x4 acc[8];
#pragma unroll
  for (int ct = 0; ct < 8; ++ct)
    acc[ct] = (f32x4){0.f, 0.f, 0.f, 0.f};

#pragma unroll
  for (int ct = 0; ct < 8; ++ct) {
#pragma unroll
    for (int kt = 0; kt < 2; ++kt) {
      bf16x8 kh = *(const bf16x8*)&KT[(ct * 16 + l16) * 64 + ((kt * 32 + quad * 8) ^ swz)];
      acc[ct] = MFMA16(qhi[kt], kh, acc[ct]);
      acc[ct] = MFMA16(qlo[kt], kh, acc[ct]);
    }
  }

  // ---- softmax: DPP 16-lane butterflies (no LDS pipe), packed bf16 mask ----
  {
    bf16x8 m8[4];
#pragma unroll
    for (int r = 0; r < 4; ++r) {
      int row = row0 + quad * 4 + r;
      m8[r] = *(const bf16x8*)&Mb[row * LN + l16 * 8];
    }
#pragma unroll
    for (int r = 0; r < 4; ++r) {
      float mx = -3.0e38f;
#pragma unroll
      for (int ct = 0; ct < 8; ++ct) mx = fmaxf(mx, acc[ct][r]);
      DPP_MAX16(mx);
      float s[8];
      float sum = 0.f;
#pragma unroll
      for (int ct = 0; ct < 8; ++ct) {
        s[ct] = __expf(acc[ct][r] - mx) * (float)m8[r][ct];
        sum += s[ct];
      }
      DPP_SUM16(sum);
      float inv = __builtin_amdgcn_rcpf(sum);
      inv = inv * (2.0f - sum * inv);
#pragma unroll
      for (int ct = 0; ct < 8; ++ct) acc[ct][r] = s[ct] * inv;
    }
  }

  f32x4 oacc[4];
#pragma unroll
  for (int nt = 0; nt < 4; ++nt)
    oacc[nt] = (f32x4){0.f, 0.f, 0.f, 0.f};

  // ---- per column-quarter: scatter P, coalesced nt attn store, PV ----
  // P rows are wave-private: no barriers needed
#pragma unroll
  for (int qu = 0; qu < 4; ++qu) {
#pragma unroll
    for (int cc = 0; cc < 2; ++cc)
#pragma unroll
      for (int r = 0; r < 4; ++r)
        P[(row0 + quad * 4 + r) * PS + cc * 16 + l16] = acc[qu * 2 + cc][r];

#pragma unroll
    for (int e = 0; e < 2; ++e) {
      int idx = e * 64 + lane;      // 128 float4 = 16 rows x 8
      int rl  = idx >> 3;
      int c4  = idx & 7;
      f32x4 v = *(const f32x4*)&P[(row0 + rl) * PS + c4 * 4];
      ntst4(&Wp[(size_t)(row0 + rl) * LN + qu * 32 + c4 * 4], v);
    }

    bf16x8 phi, plo;
    lds8_split(&P[(row0 + l16) * PS + quad * 8], phi, plo);
#pragma unroll
    for (int nt = 0; nt < 4; ++nt) {
      bf16x8 vh = *(const bf16x8*)&VT[(nt * 16 + l16) * 128 + ((qu * 32 + quad * 8) ^ swz)];
      oacc[nt] = MFMA16(phi, vh, oacc[nt]);
      oacc[nt] = MFMA16(plo, vh, oacc[nt]);
    }
  }

  // ---- O: scatter to P (wave-private), then coalesced nt float4 store ----
#pragma unroll
  for (int hf = 0; hf < 2; ++hf) {
#pragma unroll
    for (int nn = 0; nn < 2; ++nn)
#pragma unroll
      for (int r = 0; r < 4; ++r)
        P[(row0 + quad * 4 + r) * PS + nn * 16 + l16] = oacc[hf * 2 + nn][r];
#pragma unroll
    for (int e = 0; e < 2; ++e) {
      int idx = e * 64 + lane;      // 128 float4 = 16 rows x 8
      int rl  = idx >> 3;
      int c4  = idx & 7;
      f32x4 v = *(const f32x4*)&P[(row0 + rl) * PS + c4 * 4];
      ntst4(&Op[(size_t)(row0 + rl) * DN + hf * 32 + c4 * 4], v);
    }
  }
}

// ---------- fallback: original verified kernel (used if ws too small) ----------
__global__ __launch_bounds__(256, 3) void isa_attn_kernel(
    const float* __restrict__ Q, const float* __restrict__ K,
    const float* __restrict__ V, const int* __restrict__ M,
    float* __restrict__ out)
{
  __shared__ __bf16 KT[LN * KTS];
  __shared__ __bf16 VT[DN * VTS];
  __shared__ float  P [LN * PS];

  const int bid = blockIdx.x;
  const int w = (bid & 7) * 256 + (bid >> 3);
  const int h = w >> 8;
  const int c = (w >> 4) & 15;
  const int b = w & 15;

  const float* Qp = Q + (size_t)(b * HN + h) * (LN * DN);
  const float* Kp = K + (size_t)(h * BN + c) * (LN * DN);
  const float* Vp = V + (size_t)(h * BN + c) * (LN * DN);
  const int*   Mp = M + (size_t)b * (LN * LN);
  float* Op = out + (size_t)((b * HN + h) * BN + c) * (LN * DN);
  float* Wp = out + OUT0 + (size_t)((b * HN + h) * BN + c) * (LN * LN);

  const int t    = threadIdx.x;
  const int lane = t & 63;
  const int wid  = t >> 6;
  const int quad = lane >> 4;
  const int l16  = lane & 15;
  const int row0 = wid * 32;

#pragma unroll
  for (int it = 0; it < 4; ++it) {
    int idx = t + it * 256;
    int n  = idx >> 3;
    int k0 = (idx & 7) * 8;
    float4 a0 = *(const float4*)(Kp + n * DN + k0);
    float4 a1 = *(const float4*)(Kp + n * DN + k0 + 4);
    bf16x8 kk;
    kk[0] = (__bf16)a0.x; kk[1] = (__bf16)a0.y; kk[2] = (__bf16)a0.z; kk[3] = (__bf16)a0.w;
    kk[4] = (__bf16)a1.x; kk[5] = (__bf16)a1.y; kk[6] = (__bf16)a1.z; kk[7] = (__bf16)a1.w;
    *(bf16x8*)&KT[n * KTS + k0] = kk;
  }

  {
    int j8 = t >> 4;
    int d0 = (t & 15) * 4;
    float4 vv[8];
#pragma unroll
    for (int r = 0; r < 8; ++r)
      vv[r] = *(const float4*)(Vp + (j8 * 8 + r) * DN + d0);
#pragma unroll
    for (int dw = 0; dw < 4; ++dw) {
      bf16x8 col;
#pragma unroll
      for (int r = 0; r < 8; ++r)
        col[r] = (__bf16)(((const float*)&vv[r])[dw]);
      *(bf16x8*)&VT[(d0 + dw) * VTS + j8 * 8] = col;
    }
  }

  bf16x8 qhi[2][2], qlo[2][2];
#pragma unroll
  for (int rt = 0; rt < 2; ++rt)
#pragma unroll
    for (int kt = 0; kt < 2; ++kt)
      load8_split(Qp + (row0 + rt * 16 + l16) * DN + kt * 32 + quad * 8, 0.125f,
                  qhi[rt][kt], qlo[rt][kt]);

  __syncthreads();

  f32x4 acc[2][8];
#pragma unroll
  for (int rt = 0; rt < 2; ++rt)
#pragma unroll
    for (int ct = 0; ct < 8; ++ct)
      acc[rt][ct] = (f32x4){0.f, 0.f, 0.f, 0.f};

#pragma unroll
  for (int ct = 0; ct < 8; ++ct) {
#pragma unroll
    for (int kt = 0; kt < 2; ++kt) {
      bf16x8 kh = *(const bf16x8*)&KT[(ct * 16 + l16) * KTS + kt * 32 + quad * 8];
#pragma unroll
      for (int rt = 0; rt < 2; ++rt) {
        acc[rt][ct] = MFMA16(qhi[rt][kt], kh, acc[rt][ct]);
        acc[rt][ct] = MFMA16(qlo[rt][kt], kh, acc[rt][ct]);
      }
    }
  }

#pragma unroll
  for (int rt = 0; rt < 2; ++rt) {
#pragma unroll
    for (int r = 0; r < 4; ++r) {
      int row = row0 + rt * 16 + quad * 4 + r;
      const int* mrow = Mp + (size_t)row * LN + l16;
      float mf[8];
#pragma unroll
      for (int ct = 0; ct < 8; ++ct) mf[ct] = (float)mrow[ct * 16];
      float mx = -3.0e38f;
#pragma unroll
      for (int ct = 0; ct < 8; ++ct) mx = fmaxf(mx, acc[rt][ct][r]);
      mx = fmaxf(mx, __shfl_xor(mx, 1));
      mx = fmaxf(mx, __shfl_xor(mx, 2));
      mx = fmaxf(mx, __shfl_xor(mx, 4));
      mx = fmaxf(mx, __shfl_xor(mx, 8));
      float s[8];
      float sum = 0.f;
#pragma unroll
      for (int ct = 0; ct < 8; ++ct) {
        s[ct] = __expf(acc[rt][ct][r] - mx) * mf[ct];
        sum += s[ct];
      }
      sum += __shfl_xor(sum, 1);
      sum += __shfl_xor(sum, 2);
      sum += __shfl_xor(sum, 4);
      sum += __shfl_xor(sum, 8);
      float inv = __builtin_amdgcn_rcpf(sum);
      inv = inv * (2.0f - sum * inv);
#pragma unroll
      for (int ct = 0; ct < 8; ++ct) acc[rt][ct][r] = s[ct] * inv;
    }
  }

  f32x4 oacc[2][4];
#pragma unroll
  for (int rt = 0; rt < 2; ++rt)
#pragma unroll
    for (int nt = 0; nt < 4; ++nt)
      oacc[rt][nt] = (f32x4){0.f, 0.f, 0.f, 0.f};

#pragma unroll
  for (int qu = 0; qu < 4; ++qu) {
#pragma unroll
    for (int rt = 0; rt < 2; ++rt)
#pragma unroll
      for (int cc = 0; cc < 2; ++cc)
#pragma unroll
        for (int r = 0; r < 4; ++r)
          P[(row0 + rt * 16 + quad * 4 + r) * PS + cc * 16 + l16] =
              acc[rt][qu * 2 + cc][r];

#pragma unroll
    for (int e = 0; e < 4; ++e) {
      int idx = e * 64 + lane;
      int rl  = idx >> 3;
      int c4  = idx & 7;
      float4 v = *(const float4*)&P[(row0 + rl) * PS + c4 * 4];
      *(float4*)&Wp[(size_t)(row0 + rl) * LN + qu * 32 + c4 * 4] = v;
    }

    bf16x8 phi[2], plo[2];
#pragma unroll
    for (int rt = 0; rt < 2; ++rt)
      lds8_split(&P[(row0 + rt * 16 + l16) * PS + quad * 8], phi[rt], plo[rt]);
#pragma unroll
    for (int nt = 0; nt < 4; ++nt) {
      bf16x8 vh = *(const bf16x8*)&VT[(nt * 16 + l16) * VTS + qu * 32 + quad * 8];
#pragma unroll
      for (int rt = 0; rt < 2; ++rt) {
        oacc[rt][nt] = MFMA16(phi[rt], vh, oacc[rt][nt]);
        oacc[rt][nt] = MFMA16(plo[rt], vh, oacc[rt][nt]);
      }
    }
  }

#pragma unroll
  for (int hf = 0; hf < 2; ++hf) {
#pragma unroll
    for (int rt = 0; rt < 2; ++rt)
#pragma unroll
      for (int nn = 0; nn < 2; ++nn)
#pragma unroll
        for (int r = 0; r < 4; ++r)
          P[(row0 + rt * 16 + quad * 4 + r) * PS + nn * 16 + l16] =
              oacc[rt][hf * 2 + nn][r];
#pragma unroll
    for (int e = 0; e < 4; ++e) {
      int idx = e * 64 + lane;
      int rl  = idx >> 3;
      int c4  = idx & 7;
      float4 v = *(const float4*)&P[(row0 + rl) * PS + c4 * 4];
      *(float4*)&Op[(size_t)(row0 + rl) * DN + hf * 32 + c4 * 4] = v;
    }
  }
}

extern "C" void kernel_launch(void* const* d_in, const int* in_sizes, int n_in,
                              void* d_out, int out_size, void* d_ws, size_t ws_size,
                              hipStream_t stream) {
  const float* Q = (const float*)d_in[0];
  const float* K = (const float*)d_in[1];
  const float* V = (const float*)d_in[2];
  const int*   M = (const int*)d_in[3];
  if (d_ws != nullptr && ws_size >= WS_BYTES) {
    __bf16* ws = (__bf16*)d_ws;
    pre_kernel<<<dim3(1168), dim3(256), 0, stream>>>(Q, K, V, M, ws);
    isa_attn_fast<<<dim3(BN * HN * BN), dim3(512), 0, stream>>>(ws, (float*)d_out);
  } else {
    isa_attn_kernel<<<dim3(BN * HN * BN), dim3(256), 0, stream>>>(Q, K, V, M, (float*)d_out);
  }
}

// Round 6
// 220.499 us; speedup vs baseline: 1.0351x; 1.0091x over previous
//
#include <hip/hip_runtime.h>
#include <hip/hip_bf16.h>

typedef float  f32x4  __attribute__((ext_vector_type(4)));
typedef __bf16 bf16x8 __attribute__((ext_vector_type(8)));

#define MFMA16(A,B,C) __builtin_amdgcn_mfma_f32_16x16x32_bf16((A),(B),(C),0,0,0)

// full 16-lane butterfly via DPP (xor 15,7,3,1) — VALU-only, no LDS pipe
#define DPPI(x, ctrl) __int_as_float(__builtin_amdgcn_mov_dpp(__float_as_int(x), (ctrl), 0xF, 0xF, true))
#define DPP_MAX16(x) do { \
  x = fmaxf(x, DPPI(x, 0x140)); /* row_mirror      = xor15 */ \
  x = fmaxf(x, DPPI(x, 0x141)); /* row_half_mirror = xor7  */ \
  x = fmaxf(x, DPPI(x, 0x1B));  /* quad_perm 3210  = xor3  */ \
  x = fmaxf(x, DPPI(x, 0xB1));  /* quad_perm 1032  = xor1  */ \
} while (0)
#define DPP_SUM16(x) do { \
  x += DPPI(x, 0x140); \
  x += DPPI(x, 0x141); \
  x += DPPI(x, 0x1B);  \
  x += DPPI(x, 0xB1);  \
} while (0)

constexpr int BN = 16, HN = 8, LN = 128, DN = 64;
constexpr size_t OUT0 = (size_t)BN * HN * BN * LN * DN;  // O elements; attn follows

constexpr int QE = BN * HN * LN * DN;                    // 1,048,576 elems per plane
constexpr size_t MBOFF = 4 * (size_t)QE;                 // bf16 elems: mask plane offset
constexpr size_t WS_BYTES = (MBOFF + (size_t)BN * LN * LN) * sizeof(__bf16);  // 8.5 MiB

constexpr int PS  = 36;   // P row stride (fp32) = 144 B (scatter stays 2-way/free)
// fallback-path strides (original kernel)
constexpr int KTS = 72;
constexpr int VTS = 136;

// ---------- helpers ----------

__device__ __forceinline__ void load8_split(const float* __restrict__ p, float scale,
                                            bf16x8& hi, bf16x8& lo) {
  float f[8];
  *(float4*)&f[0] = *(const float4*)(p);
  *(float4*)&f[4] = *(const float4*)(p + 4);
#pragma unroll
  for (int i = 0; i < 8; ++i) {
    float x = f[i] * scale;
    __bf16 h = (__bf16)x;
    hi[i] = h;
    lo[i] = (__bf16)(x - (float)h);
  }
}

__device__ __forceinline__ void lds8_split(const float* p, bf16x8& hi, bf16x8& lo) {
  float f[8];
  *(float4*)&f[0] = *(const float4*)(p);
  *(float4*)&f[4] = *(const float4*)(p + 4);
#pragma unroll
  for (int i = 0; i < 8; ++i) {
    __bf16 h = (__bf16)f[i];
    hi[i] = h;
    lo[i] = (__bf16)(f[i] - (float)h);
  }
}

// width-16 global -> LDS DMA (linear dest = wave-uniform base + lane*16)
__device__ __forceinline__ void gload_lds16(const void* g, void* l) {
  __builtin_amdgcn_global_load_lds(
      (const __attribute__((address_space(1))) unsigned int*)g,
      (__attribute__((address_space(3))) unsigned int*)l, 16, 0, 0);
}

// nontemporal 16B ops use clang ext-vector types (HIP_vector_type is rejected)
__device__ __forceinline__ f32x4 ntld4(const float* p) {
  return __builtin_nontemporal_load((const f32x4*)p);
}
__device__ __forceinline__ void ntst4(float* p, f32x4 v) {
  __builtin_nontemporal_store(v, (f32x4*)p);
}

// ---------- pre-pass: convert/split/transpose once (shared by 16 blocks each) ----------
// ws layout (bf16 elems): [0,QE) Qhi | [QE,2QE) Qlo | [2QE,3QE) KT | [3QE,4QE) VT
//                         [4QE, 4QE+16*16384) mask repacked to lane layout
// KT/VT are stored XOR-swizzled (elem-group ^= (row&7)<<3) so the main kernel's
// LINEAR global_load_lds deposits a swizzled LDS image and ds_read XORs it back.
__global__ __launch_bounds__(256) void pre_kernel(
    const float* __restrict__ Q, const float* __restrict__ K,
    const float* __restrict__ V, const int* __restrict__ M,
    __bf16* __restrict__ ws)
{
  const int t   = threadIdx.x;
  const int blk = blockIdx.x;

  if (blk < 512) {
    // ---- Q: pre-scaled hi/lo split, layout preserved (B,H,L,D) ----
    int base = blk * 2048 + t * 8;
    float f[8];
    *(f32x4*)&f[0] = ntld4(Q + base);
    *(f32x4*)&f[4] = ntld4(Q + base + 4);
    bf16x8 hi, lo;
#pragma unroll
    for (int i = 0; i < 8; ++i) {
      float x = f[i] * 0.125f;
      __bf16 h = (__bf16)x;
      hi[i] = h;
      lo[i] = (__bf16)(x - (float)h);
    }
    *(bf16x8*)&ws[base]      = hi;
    *(bf16x8*)&ws[QE + base] = lo;
  } else if (blk < 1024) {
    // ---- K -> bf16, k-group swizzled within each row ----
    int g  = (blk - 512) * 256 + t;      // bits: [0:2]=k-group [3:9]=n [10:16]=hc
    int k0 = (g & 7) * 8;
    int n  = (g >> 3) & 127;
    int hc = g >> 10;
    const float* src = K + ((size_t)hc * LN + n) * DN + k0;
    float f[8];
    *(f32x4*)&f[0] = ntld4(src);
    *(f32x4*)&f[4] = ntld4(src + 4);
    bf16x8 kk;
#pragma unroll
    for (int i = 0; i < 8; ++i) kk[i] = (__bf16)f[i];
    int k0s = k0 ^ ((n & 7) << 3);
    *(bf16x8*)&ws[2 * (size_t)QE + (size_t)hc * 8192 + n * 64 + k0s] = kk;
  } else if (blk < 1152) {
    // ---- V -> V^T bf16 [d][j], j-group swizzled within each row ----
    int hc = blk - 1024;
    int j8 = t >> 4;                 // j block of 8
    int d0 = (t & 15) * 4;
    const float* Vp = V + (size_t)hc * (LN * DN);
    f32x4 vv[8];
#pragma unroll
    for (int r = 0; r < 8; ++r)
      vv[r] = ntld4(Vp + (j8 * 8 + r) * DN + d0);
#pragma unroll
    for (int dw = 0; dw < 4; ++dw) {
      int d = d0 + dw;
      bf16x8 col;
#pragma unroll
      for (int r = 0; r < 8; ++r)
        col[r] = (__bf16)vv[r][dw];
      int js = (j8 * 8) ^ ((d & 7) << 3);
      *(bf16x8*)&ws[3 * (size_t)QE + (size_t)hc * 8192 + d * 128 + js] = col;
    }
  } else {
    // ---- mask repack, PARALLEL (128 blocks; was 16 -> latency-bound tail) ----
    // thread -> ONE bf16x8 group: dst[b][row][l16*8+ct] = (bf16)src[b][row][ct*16+l16]
    int g    = blk - 1152;            // 0..127
    int bsel = g >> 3;                // 16 samples
    int row  = (g & 7) * 16 + (t >> 4);
    int l16  = t & 15;
    const int* src = M + ((size_t)bsel * LN + row) * LN;
    __bf16*    dst = ws + MBOFF + ((size_t)bsel * LN + row) * LN;
    bf16x8 m8;
#pragma unroll
    for (int ct = 0; ct < 8; ++ct)
      m8[ct] = (__bf16)(float)src[ct * 16 + l16];
    *(bf16x8*)&dst[l16 * 8] = m8;
  }
}

// ---------- fast main kernel: 8 waves x 16 rows, 4 waves/SIMD occupancy ----------
__global__ __launch_bounds__(512, 4) void isa_attn_fast(
    const __bf16* __restrict__ ws, float* __restrict__ out)
{
  __shared__ __bf16 KT[LN * DN];   // 16384 B, swizzled image
  __shared__ __bf16 VT[DN * LN];   // 16384 B, swizzled image
  __shared__ float  P [LN * PS];   // 18432 B
  // total 51200 B; VGPR <= 128 -> 2 blocks/CU = 16 waves/CU = 4 waves/SIMD

  const int bid = blockIdx.x;
  // XCD swizzle: each XCD owns one h -> K,V(h,*) + Q(*,h) + mask fit its L2
  const int w = (bid & 7) * 256 + (bid >> 3);
  const int h = w >> 8;
  const int c = (w >> 4) & 15;
  const int b = w & 15;
  const int hc = h * BN + c;

  const __bf16* Qh = ws + (size_t)(b * HN + h) * (LN * DN);
  const __bf16* Ql = Qh + QE;
  const __bf16* Ks = ws + 2 * (size_t)QE + (size_t)hc * 8192;
  const __bf16* Vs = ws + 3 * (size_t)QE + (size_t)hc * 8192;
  const __bf16* Mb = ws + MBOFF + (size_t)b * (LN * LN);
  float* Op = out + (size_t)((b * HN + h) * BN + c) * (LN * DN);
  float* Wp = out + OUT0 + (size_t)((b * HN + h) * BN + c) * (LN * LN);

  const int t    = threadIdx.x;
  const int lane = t & 63;
  const int wid  = t >> 6;          // 8 waves; wave owns rows [16*wid, 16*wid+16)
  const int quad = lane >> 4;
  const int l16  = lane & 15;
  const int row0 = wid * 16;
  const int swz  = (l16 & 7) << 3;

  // ---- stage K / V^T via direct-to-LDS DMA (512 threads: 2+2 DMAs each) ----
  {
    const char* kg = (const char*)Ks;
    const char* vg = (const char*)Vs;
    char* kl = (char*)KT;
    char* vl = (char*)VT;
#pragma unroll
    for (int i = 0; i < 2; ++i)
      gload_lds16(kg + t * 16 + i * 8192, kl + t * 16 + i * 8192);
#pragma unroll
    for (int i = 0; i < 2; ++i)
      gload_lds16(vg + t * 16 + i * 8192, vl + t * 16 + i * 8192);
  }

  // ---- Q A-fragments: direct bf16 loads (pre-scaled, pre-split) ----
  bf16x8 qhi[2], qlo[2];
#pragma unroll
  for (int kt = 0; kt < 2; ++kt) {
    const int off = (row0 + l16) * DN + kt * 32 + quad * 8;
    qhi[kt] = *(const bf16x8*)(Qh + off);
    qlo[kt] = *(const bf16x8*)(Ql + off);
  }

  __syncthreads();   // drains vmcnt: DMA deposits complete

  // ---- S = (Qhi+Qlo) K^T ----
  f32x4 acc[8];
#pragma unroll
  for (int ct = 0; ct < 8; ++ct)
    acc[ct] = (f32x4){0.f, 0.f, 0.f, 0.f};

#pragma unroll
  for (int ct = 0; ct < 8; ++ct) {
#pragma unroll
    for (int kt = 0; kt < 2; ++kt) {
      bf16x8 kh = *(const bf16x8*)&KT[(ct * 16 + l16) * 64 + ((kt * 32 + quad * 8) ^ swz)];
      acc[ct] = MFMA16(qhi[kt], kh, acc[ct]);
      acc[ct] = MFMA16(qlo[kt], kh, acc[ct]);
    }
  }

  // ---- softmax: DPP 16-lane butterflies (no LDS pipe), packed bf16 mask ----
  {
    bf16x8 m8[4];
#pragma unroll
    for (int r = 0; r < 4; ++r) {
      int row = row0 + quad * 4 + r;
      m8[r] = *(const bf16x8*)&Mb[row * LN + l16 * 8];
    }
#pragma unroll
    for (int r = 0; r < 4; ++r) {
      float mx = -3.0e38f;
#pragma unroll
      for (int ct = 0; ct < 8; ++ct) mx = fmaxf(mx, acc[ct][r]);
      DPP_MAX16(mx);
      float s[8];
      float sum = 0.f;
#pragma unroll
      for (int ct = 0; ct < 8; ++ct) {
        s[ct] = __expf(acc[ct][r] - mx) * (float)m8[r][ct];
        sum += s[ct];
      }
      DPP_SUM16(sum);
      float inv = __builtin_amdgcn_rcpf(sum);
      inv = inv * (2.0f - sum * inv);
#pragma unroll
      for (int ct = 0; ct < 8; ++ct) acc[ct][r] = s[ct] * inv;
    }
  }

  f32x4 oacc[4];
#pragma unroll
  for (int nt = 0; nt < 4; ++nt)
    oacc[nt] = (f32x4){0.f, 0.f, 0.f, 0.f};

  // ---- per column-quarter: scatter P, coalesced nt attn store, PV ----
  // P rows are wave-private: no barriers needed
#pragma unroll
  for (int qu = 0; qu < 4; ++qu) {
#pragma unroll
    for (int cc = 0; cc < 2; ++cc)
#pragma unroll
      for (int r = 0; r < 4; ++r)
        P[(row0 + quad * 4 + r) * PS + cc * 16 + l16] = acc[qu * 2 + cc][r];

#pragma unroll
    for (int e = 0; e < 2; ++e) {
      int idx = e * 64 + lane;      // 128 float4 = 16 rows x 8
      int rl  = idx >> 3;
      int c4  = idx & 7;
      f32x4 v = *(const f32x4*)&P[(row0 + rl) * PS + c4 * 4];
      ntst4(&Wp[(size_t)(row0 + rl) * LN + qu * 32 + c4 * 4], v);
    }

    bf16x8 phi, plo;
    lds8_split(&P[(row0 + l16) * PS + quad * 8], phi, plo);
#pragma unroll
    for (int nt = 0; nt < 4; ++nt) {
      bf16x8 vh = *(const bf16x8*)&VT[(nt * 16 + l16) * 128 + ((qu * 32 + quad * 8) ^ swz)];
      oacc[nt] = MFMA16(phi, vh, oacc[nt]);
      oacc[nt] = MFMA16(plo, vh, oacc[nt]);
    }
  }

  // ---- O: scatter to P (wave-private), then coalesced nt float4 store ----
#pragma unroll
  for (int hf = 0; hf < 2; ++hf) {
#pragma unroll
    for (int nn = 0; nn < 2; ++nn)
#pragma unroll
      for (int r = 0; r < 4; ++r)
        P[(row0 + quad * 4 + r) * PS + nn * 16 + l16] = oacc[hf * 2 + nn][r];
#pragma unroll
    for (int e = 0; e < 2; ++e) {
      int idx = e * 64 + lane;      // 128 float4 = 16 rows x 8
      int rl  = idx >> 3;
      int c4  = idx & 7;
      f32x4 v = *(const f32x4*)&P[(row0 + rl) * PS + c4 * 4];
      ntst4(&Op[(size_t)(row0 + rl) * DN + hf * 32 + c4 * 4], v);
    }
  }
}

// ---------- fallback: original verified kernel (used if ws too small) ----------
__global__ __launch_bounds__(256, 3) void isa_attn_kernel(
    const float* __restrict__ Q, const float* __restrict__ K,
    const float* __restrict__ V, const int* __restrict__ M,
    float* __restrict__ out)
{
  __shared__ __bf16 KT[LN * KTS];
  __shared__ __bf16 VT[DN * VTS];
  __shared__ float  P [LN * PS];

  const int bid = blockIdx.x;
  const int w = (bid & 7) * 256 + (bid >> 3);
  const int h = w >> 8;
  const int c = (w >> 4) & 15;
  const int b = w & 15;

  const float* Qp = Q + (size_t)(b * HN + h) * (LN * DN);
  const float* Kp = K + (size_t)(h * BN + c) * (LN * DN);
  const float* Vp = V + (size_t)(h * BN + c) * (LN * DN);
  const int*   Mp = M + (size_t)b * (LN * LN);
  float* Op = out + (size_t)((b * HN + h) * BN + c) * (LN * DN);
  float* Wp = out + OUT0 + (size_t)((b * HN + h) * BN + c) * (LN * LN);

  const int t    = threadIdx.x;
  const int lane = t & 63;
  const int wid  = t >> 6;
  const int quad = lane >> 4;
  const int l16  = lane & 15;
  const int row0 = wid * 32;

#pragma unroll
  for (int it = 0; it < 4; ++it) {
    int idx = t + it * 256;
    int n  = idx >> 3;
    int k0 = (idx & 7) * 8;
    float4 a0 = *(const float4*)(Kp + n * DN + k0);
    float4 a1 = *(const float4*)(Kp + n * DN + k0 + 4);
    bf16x8 kk;
    kk[0] = (__bf16)a0.x; kk[1] = (__bf16)a0.y; kk[2] = (__bf16)a0.z; kk[3] = (__bf16)a0.w;
    kk[4] = (__bf16)a1.x; kk[5] = (__bf16)a1.y; kk[6] = (__bf16)a1.z; kk[7] = (__bf16)a1.w;
    *(bf16x8*)&KT[n * KTS + k0] = kk;
  }

  {
    int j8 = t >> 4;
    int d0 = (t & 15) * 4;
    float4 vv[8];
#pragma unroll
    for (int r = 0; r < 8; ++r)
      vv[r] = *(const float4*)(Vp + (j8 * 8 + r) * DN + d0);
#pragma unroll
    for (int dw = 0; dw < 4; ++dw) {
      bf16x8 col;
#pragma unroll
      for (int r = 0; r < 8; ++r)
        col[r] = (__bf16)(((const float*)&vv[r])[dw]);
      *(bf16x8*)&VT[(d0 + dw) * VTS + j8 * 8] = col;
    }
  }

  bf16x8 qhi[2][2], qlo[2][2];
#pragma unroll
  for (int rt = 0; rt < 2; ++rt)
#pragma unroll
    for (int kt = 0; kt < 2; ++kt)
      load8_split(Qp + (row0 + rt * 16 + l16) * DN + kt * 32 + quad * 8, 0.125f,
                  qhi[rt][kt], qlo[rt][kt]);

  __syncthreads();

  f32x4 acc[2][8];
#pragma unroll
  for (int rt = 0; rt < 2; ++rt)
#pragma unroll
    for (int ct = 0; ct < 8; ++ct)
      acc[rt][ct] = (f32x4){0.f, 0.f, 0.f, 0.f};

#pragma unroll
  for (int ct = 0; ct < 8; ++ct) {
#pragma unroll
    for (int kt = 0; kt < 2; ++kt) {
      bf16x8 kh = *(const bf16x8*)&KT[(ct * 16 + l16) * KTS + kt * 32 + quad * 8];
#pragma unroll
      for (int rt = 0; rt < 2; ++rt) {
        acc[rt][ct] = MFMA16(qhi[rt][kt], kh, acc[rt][ct]);
        acc[rt][ct] = MFMA16(qlo[rt][kt], kh, acc[rt][ct]);
      }
    }
  }

#pragma unroll
  for (int rt = 0; rt < 2; ++rt) {
#pragma unroll
    for (int r = 0; r < 4; ++r) {
      int row = row0 + rt * 16 + quad * 4 + r;
      const int* mrow = Mp + (size_t)row * LN + l16;
      float mf[8];
#pragma unroll
      for (int ct = 0; ct < 8; ++ct) mf[ct] = (float)mrow[ct * 16];
      float mx = -3.0e38f;
#pragma unroll
      for (int ct = 0; ct < 8; ++ct) mx = fmaxf(mx, acc[rt][ct][r]);
      mx = fmaxf(mx, __shfl_xor(mx, 1));
      mx = fmaxf(mx, __shfl_xor(mx, 2));
      mx = fmaxf(mx, __shfl_xor(mx, 4));
      mx = fmaxf(mx, __shfl_xor(mx, 8));
      float s[8];
      float sum = 0.f;
#pragma unroll
      for (int ct = 0; ct < 8; ++ct) {
        s[ct] = __expf(acc[rt][ct][r] - mx) * mf[ct];
        sum += s[ct];
      }
      sum += __shfl_xor(sum, 1);
      sum += __shfl_xor(sum, 2);
      sum += __shfl_xor(sum, 4);
      sum += __shfl_xor(sum, 8);
      float inv = __builtin_amdgcn_rcpf(sum);
      inv = inv * (2.0f - sum * inv);
#pragma unroll
      for (int ct = 0; ct < 8; ++ct) acc[rt][ct][r] = s[ct] * inv;
    }
  }

  f32x4 oacc[2][4];
#pragma unroll
  for (int rt = 0; rt < 2; ++rt)
#pragma unroll
    for (int nt = 0; nt < 4; ++nt)
      oacc[rt][nt] = (f32x4){0.f, 0.f, 0.f, 0.f};

#pragma unroll
  for (int qu = 0; qu < 4; ++qu) {
#pragma unroll
    for (int rt = 0; rt < 2; ++rt)
#pragma unroll
      for (int cc = 0; cc < 2; ++cc)
#pragma unroll
        for (int r = 0; r < 4; ++r)
          P[(row0 + rt * 16 + quad * 4 + r) * PS + cc * 16 + l16] =
              acc[rt][qu * 2 + cc][r];

#pragma unroll
    for (int e = 0; e < 4; ++e) {
      int idx = e * 64 + lane;
      int rl  = idx >> 3;
      int c4  = idx & 7;
      float4 v = *(const float4*)&P[(row0 + rl) * PS + c4 * 4];
      *(float4*)&Wp[(size_t)(row0 + rl) * LN + qu * 32 + c4 * 4] = v;
    }

    bf16x8 phi[2], plo[2];
#pragma unroll
    for (int rt = 0; rt < 2; ++rt)
      lds8_split(&P[(row0 + rt * 16 + l16) * PS + quad * 8], phi[rt], plo[rt]);
#pragma unroll
    for (int nt = 0; nt < 4; ++nt) {
      bf16x8 vh = *(const bf16x8*)&VT[(nt * 16 + l16) * VTS + qu * 32 + quad * 8];
#pragma unroll
      for (int rt = 0; rt < 2; ++rt) {
        oacc[rt][nt] = MFMA16(phi[rt], vh, oacc[rt][nt]);
        oacc[rt][nt] = MFMA16(plo[rt], vh, oacc[rt][nt]);
      }
    }
  }

#pragma unroll
  for (int hf = 0; hf < 2; ++hf) {
#pragma unroll
    for (int rt = 0; rt < 2; ++rt)
#pragma unroll
      for (int nn = 0; nn < 2; ++nn)
#pragma unroll
        for (int r = 0; r < 4; ++r)
          P[(row0 + rt * 16 + quad * 4 + r) * PS + nn * 16 + l16] =
              oacc[rt][hf * 2 + nn][r];
#pragma unroll
    for (int e = 0; e < 4; ++e) {
      int idx = e * 64 + lane;
      int rl  = idx >> 3;
      int c4  = idx & 7;
      float4 v = *(const float4*)&P[(row0 + rl) * PS + c4 * 4];
      *(float4*)&Op[(size_t)(row0 + rl) * DN + hf * 32 + c4 * 4] = v;
    }
  }
}

extern "C" void kernel_launch(void* const* d_in, const int* in_sizes, int n_in,
                              void* d_out, int out_size, void* d_ws, size_t ws_size,
                              hipStream_t stream) {
  const float* Q = (const float*)d_in[0];
  const float* K = (const float*)d_in[1];
  const float* V = (const float*)d_in[2];
  const int*   M = (const int*)d_in[3];
  if (d_ws != nullptr && ws_size >= WS_BYTES) {
    __bf16* ws = (__bf16*)d_ws;
    pre_kernel<<<dim3(1280), dim3(256), 0, stream>>>(Q, K, V, M, ws);
    isa_attn_fast<<<dim3(BN * HN * BN), dim3(512), 0, stream>>>(ws, (float*)d_out);
  } else {
    isa_attn_kernel<<<dim3(BN * HN * BN), dim3(256), 0, stream>>>(Q, K, V, M, (float*)d_out);
  }
}